// Round 2
// baseline (996.344 us; speedup 1.0000x reference)
//
#include <hip/hip_runtime.h>
#include <math.h>

#define MAX_VEL 0.9f
#define REL_EPS 1e-6f

// ---------------- dense linear: Y[N,64] = X[N,64] @ W[64,64] + b ----------------
__global__ void linear64(const float* __restrict__ X, const float* __restrict__ W,
                         const float* __restrict__ b, float* __restrict__ Y, int N)
{
    __shared__ float sW[64 * 64];
    __shared__ float sB[64];
    for (int i = threadIdx.x; i < 64 * 64; i += blockDim.x) sW[i] = W[i];
    if (threadIdx.x < 64) sB[threadIdx.x] = b[threadIdx.x];
    __syncthreads();
    int node = blockIdx.x * 4 + (threadIdx.x >> 6);
    int c = threadIdx.x & 63;
    if (node >= N) return;
    const float* xr = X + (size_t)node * 64;
    float acc = sB[c];
#pragma unroll
    for (int k = 0; k < 64; ++k) acc = fmaf(xr[k], sW[k * 64 + c], acc);
    Y[(size_t)node * 64 + c] = acc;
}

// ---------------- dense linear: Y[N,32] = X[N,64] @ W[64,32] + b ----------------
__global__ void linear32(const float* __restrict__ X, const float* __restrict__ W,
                         const float* __restrict__ b, float* __restrict__ Y, int N)
{
    __shared__ float sW[64 * 32];
    __shared__ float sB[32];
    for (int i = threadIdx.x; i < 64 * 32; i += blockDim.x) sW[i] = W[i];
    if (threadIdx.x < 32) sB[threadIdx.x] = b[threadIdx.x];
    __syncthreads();
    int node = blockIdx.x * 8 + (threadIdx.x >> 5);
    int c = threadIdx.x & 31;
    if (node >= N) return;
    const float* xr = X + (size_t)node * 64;
    float acc = sB[c];
#pragma unroll
    for (int k = 0; k < 64; ++k) acc = fmaf(xr[k], sW[k * 32 + c], acc);
    Y[(size_t)node * 32 + c] = acc;
}

// ---------------- CSR build: histogram of dst ----------------
__global__ void count_dst(const int* __restrict__ dst, int* __restrict__ cnt, int E)
{
    int e = blockIdx.x * blockDim.x + threadIdx.x;
    if (e < E) atomicAdd(&cnt[dst[e]], 1);
}

// ---------------- CSR build: exclusive scan (single 1024-thread block) ----------------
__global__ __launch_bounds__(1024) void scan_excl(const int* __restrict__ cnt,
                                                  int* __restrict__ cursor, int N)
{
    __shared__ int s[1024];
    int t = threadIdx.x;
    int chunk = (N + 1023) >> 10;
    int beg = t * chunk;
    int end = min(beg + chunk, N);
    int sum = 0;
    for (int i = beg; i < end; ++i) sum += cnt[i];
    s[t] = sum;
    __syncthreads();
    for (int off = 1; off < 1024; off <<= 1) {
        int add = (t >= off) ? s[t - off] : 0;
        __syncthreads();
        s[t] += add;
        __syncthreads();
    }
    int run = (t == 0) ? 0 : s[t - 1];
    for (int i = beg; i < end; ++i) { cursor[i] = run; run += cnt[i]; }
}

// ---------------- CSR build: scatter src ids into dst-sorted order ----------------
// After this kernel, cursor[i] == rowptr[i+1] (inclusive prefix).
__global__ void scatter_edges(const int* __restrict__ src, const int* __restrict__ dst,
                              int* __restrict__ cursor, int* __restrict__ src_sorted, int E)
{
    int e = blockIdx.x * blockDim.x + threadIdx.x;
    if (e < E) {
        int p = atomicAdd(&cursor[dst[e]], 1);
        src_sorted[p] = src[e];
    }
}

// ---- layer-1 fused gather-aggregate: w from x, message from h1 (64ch), +norm +relu ----
__global__ void agg1_relu(const float* __restrict__ x, const float* __restrict__ h1,
                          const int* __restrict__ cursor, const int* __restrict__ cnt,
                          const int* __restrict__ src_sorted,
                          float* __restrict__ hidden, int N)
{
    int wid = (blockIdx.x * blockDim.x + threadIdx.x) >> 6;
    int lane = threadIdx.x & 63;
    if (wid >= N) return;
    int deg = cnt[wid];
    int end = cursor[wid];     // inclusive prefix after scatter
    int beg = end - deg;
    float xn = x[(size_t)wid * 64 + lane];
    float acc = 0.0f;
    for (int p = beg; p < end; ++p) {
        int s = src_sorted[p];
        float xs = x[(size_t)s * 64 + lane];
        float hs = h1[(size_t)s * 64 + lane];
        float df = xs - xn;
        float sq = df * df;
#pragma unroll
        for (int off = 32; off; off >>= 1) sq += __shfl_xor(sq, off);
        float v = tanhf(sqrtf(sq)) * MAX_VEL;
        float w = sqrtf(1.0f - v * v + REL_EPS);   // == 1/gamma
        acc = fmaf(hs, w, acc);
    }
    float dv = deg > 1 ? (float)deg : 1.0f;
    float val = acc / dv;
    hidden[(size_t)wid * 64 + lane] = val > 0.0f ? val : 0.0f;
}

// ---- layer-2 fused gather-aggregate: w from hidden (64ch), message from h2 (32ch) ----
__global__ void agg2_out(const float* __restrict__ hidden, const float* __restrict__ h2,
                         const int* __restrict__ cursor, const int* __restrict__ cnt,
                         const int* __restrict__ src_sorted,
                         float* __restrict__ out, int N)
{
    int wid = (blockIdx.x * blockDim.x + threadIdx.x) >> 6;
    int lane = threadIdx.x & 63;
    if (wid >= N) return;
    int deg = cnt[wid];
    int end = cursor[wid];
    int beg = end - deg;
    float hn = hidden[(size_t)wid * 64 + lane];
    float acc = 0.0f;
    for (int p = beg; p < end; ++p) {
        int s = src_sorted[p];
        float hs = hidden[(size_t)s * 64 + lane];
        float df = hs - hn;
        float sq = df * df;
#pragma unroll
        for (int off = 32; off; off >>= 1) sq += __shfl_xor(sq, off);
        float v = tanhf(sqrtf(sq)) * MAX_VEL;
        float w = sqrtf(1.0f - v * v + REL_EPS);
        float ms = (lane < 32) ? h2[(size_t)s * 32 + lane] : 0.0f;
        acc = fmaf(ms, w, acc);
    }
    if (lane < 32) {
        float dv = deg > 1 ? (float)deg : 1.0f;
        out[(size_t)wid * 32 + lane] = acc / dv;
    }
}

extern "C" void kernel_launch(void* const* d_in, const int* in_sizes, int n_in,
                              void* d_out, int out_size, void* d_ws, size_t ws_size,
                              hipStream_t stream)
{
    const float* x  = (const float*)d_in[0];
    const int*   ei = (const int*)d_in[1];
    const float* W1 = (const float*)d_in[2];
    const float* b1 = (const float*)d_in[3];
    const float* W2 = (const float*)d_in[4];
    const float* b2 = (const float*)d_in[5];
    float* out = (float*)d_out;

    const int N = in_sizes[0] / 64;
    const int E = in_sizes[1] / 2;
    const int* src = ei;
    const int* dst = ei + E;

    // workspace layout (floats/ints, 4B each):
    //   h1      : N*64   (layer-1 linear out; later reused for h2 = N*32)
    //   hidden  : N*64   (relu'd normalized layer-1 output)
    //   cnt     : N      (in-degree histogram)
    //   cursor  : N      (scan -> scatter cursors -> inclusive rowptr)
    //   src_sorted : E   (src ids sorted by dst)
    float* ws = (float*)d_ws;
    float* h1     = ws;
    float* hidden = h1 + (size_t)N * 64;
    int*   cnt    = (int*)(hidden + (size_t)N * 64);
    int*   cursor = cnt + N;
    int*   src_sorted = cursor + N;
    float* h2     = h1;   // alias: h1 dead after agg1_relu

    hipMemsetAsync(cnt, 0, (size_t)N * sizeof(int), stream);

    int eblk = (E + 255) / 256;
    count_dst<<<eblk, 256, 0, stream>>>(dst, cnt, E);
    scan_excl<<<1, 1024, 0, stream>>>(cnt, cursor, N);
    scatter_edges<<<eblk, 256, 0, stream>>>(src, dst, cursor, src_sorted, E);

    linear64<<<(N + 3) / 4, 256, 0, stream>>>(x, W1, b1, h1, N);

    int nblk = (int)(((size_t)N * 64 + 255) / 256);
    agg1_relu<<<nblk, 256, 0, stream>>>(x, h1, cursor, cnt, src_sorted, hidden, N);

    linear32<<<(N + 7) / 8, 256, 0, stream>>>(hidden, W2, b2, h2, N);

    agg2_out<<<nblk, 256, 0, stream>>>(hidden, h2, cursor, cnt, src_sorted, out, N);
}

// Round 3
// 682.269 us; speedup vs baseline: 1.4603x; 1.4603x over previous
//
#include <hip/hip_runtime.h>
#include <math.h>

#define MAX_VEL 0.9f
#define REL_EPS 1e-6f

// Lorentz time-dilation weight from squared distance.
// w = sqrt(1 - (0.9*tanh(r))^2 + eps), tanh via fast exp: th = 1 - 2/(e^{2r}+1).
__device__ __forceinline__ float lorentz_w(float sq)
{
    float r = sqrtf(sq);
    float e = __expf(2.0f * r);
    float th = 1.0f - 2.0f / (e + 1.0f);
    return sqrtf(fmaf(-(MAX_VEL * MAX_VEL), th * th, 1.0f + REL_EPS));
}

// ---------------- dense linear: Y[N,64] = X[N,64] @ W[64,64] + b ----------------
__global__ void linear64(const float* __restrict__ X, const float* __restrict__ W,
                         const float* __restrict__ b, float* __restrict__ Y, int N)
{
    __shared__ float sW[64 * 64];
    __shared__ float sB[64];
    for (int i = threadIdx.x; i < 64 * 64; i += blockDim.x) sW[i] = W[i];
    if (threadIdx.x < 64) sB[threadIdx.x] = b[threadIdx.x];
    __syncthreads();
    int node = blockIdx.x * 4 + (threadIdx.x >> 6);
    int c = threadIdx.x & 63;
    if (node >= N) return;
    const float* xr = X + (size_t)node * 64;
    float acc = sB[c];
#pragma unroll
    for (int k = 0; k < 64; k += 4) {
        float4 xv = *reinterpret_cast<const float4*>(xr + k);  // broadcast within wave
        acc = fmaf(xv.x, sW[(k + 0) * 64 + c], acc);
        acc = fmaf(xv.y, sW[(k + 1) * 64 + c], acc);
        acc = fmaf(xv.z, sW[(k + 2) * 64 + c], acc);
        acc = fmaf(xv.w, sW[(k + 3) * 64 + c], acc);
    }
    Y[(size_t)node * 64 + c] = acc;
}

// ---------------- dense linear: Y[N,32] = X[N,64] @ W[64,32] + b ----------------
__global__ void linear32(const float* __restrict__ X, const float* __restrict__ W,
                         const float* __restrict__ b, float* __restrict__ Y, int N)
{
    __shared__ float sW[64 * 32];
    __shared__ float sB[32];
    for (int i = threadIdx.x; i < 64 * 32; i += blockDim.x) sW[i] = W[i];
    if (threadIdx.x < 32) sB[threadIdx.x] = b[threadIdx.x];
    __syncthreads();
    int node = blockIdx.x * 8 + (threadIdx.x >> 5);
    int c = threadIdx.x & 31;
    if (node >= N) return;
    const float* xr = X + (size_t)node * 64;
    float acc = sB[c];
#pragma unroll
    for (int k = 0; k < 64; k += 4) {
        float4 xv = *reinterpret_cast<const float4*>(xr + k);
        acc = fmaf(xv.x, sW[(k + 0) * 32 + c], acc);
        acc = fmaf(xv.y, sW[(k + 1) * 32 + c], acc);
        acc = fmaf(xv.z, sW[(k + 2) * 32 + c], acc);
        acc = fmaf(xv.w, sW[(k + 3) * 32 + c], acc);
    }
    Y[(size_t)node * 32 + c] = acc;
}

// ---------------- CSR build: histogram of dst ----------------
__global__ void count_dst(const int* __restrict__ dst, int* __restrict__ cnt, int E)
{
    int e = blockIdx.x * blockDim.x + threadIdx.x;
    if (e < E) atomicAdd(&cnt[dst[e]], 1);
}

// ---------------- CSR build: exclusive scan (single 1024-thread block) ----------------
__global__ __launch_bounds__(1024) void scan_excl(const int* __restrict__ cnt,
                                                  int* __restrict__ cursor, int N)
{
    __shared__ int s[1024];
    int t = threadIdx.x;
    int chunk = (N + 1023) >> 10;
    int beg = t * chunk;
    int end = min(beg + chunk, N);
    int sum = 0;
    for (int i = beg; i < end; ++i) sum += cnt[i];
    s[t] = sum;
    __syncthreads();
    for (int off = 1; off < 1024; off <<= 1) {
        int add = (t >= off) ? s[t - off] : 0;
        __syncthreads();
        s[t] += add;
        __syncthreads();
    }
    int run = (t == 0) ? 0 : s[t - 1];
    for (int i = beg; i < end; ++i) { cursor[i] = run; run += cnt[i]; }
}

// ---------------- CSR build: scatter src ids into dst-sorted order ----------------
// After this kernel, cursor[i] == rowptr[i+1] (inclusive prefix).
__global__ void scatter_edges(const int* __restrict__ src, const int* __restrict__ dst,
                              int* __restrict__ cursor, int* __restrict__ src_sorted, int E)
{
    int e = blockIdx.x * blockDim.x + threadIdx.x;
    if (e < E) {
        int p = atomicAdd(&cursor[dst[e]], 1);
        src_sorted[p] = src[e];
    }
}

// ---- layer-1 fused gather-aggregate: 16-lane group per node, float4 per lane. ----
// w from x-rows, message from h1 (64ch); normalize by deg; relu.
__global__ void agg1_relu(const float* __restrict__ x, const float* __restrict__ h1,
                          const int* __restrict__ cursor, const int* __restrict__ cnt,
                          const int* __restrict__ src_sorted,
                          float* __restrict__ hidden, int N)
{
    int node = (blockIdx.x * blockDim.x + threadIdx.x) >> 4;
    int gl = threadIdx.x & 15;
    if (node >= N) return;
    int deg = cnt[node];
    int end = cursor[node];     // inclusive prefix after scatter
    int beg = end - deg;
    float4 xd = *reinterpret_cast<const float4*>(x + (size_t)node * 64 + gl * 4);
    float ax = 0.f, ay = 0.f, az = 0.f, aw = 0.f;
    for (int p = beg; p < end; ++p) {
        int s = src_sorted[p];
        float4 xs = *reinterpret_cast<const float4*>(x + (size_t)s * 64 + gl * 4);
        float4 hs = *reinterpret_cast<const float4*>(h1 + (size_t)s * 64 + gl * 4);
        float dx = xs.x - xd.x, dy = xs.y - xd.y, dz = xs.z - xd.z, dw = xs.w - xd.w;
        float sq = dx * dx;
        sq = fmaf(dy, dy, sq);
        sq = fmaf(dz, dz, sq);
        sq = fmaf(dw, dw, sq);
        sq += __shfl_xor(sq, 1);
        sq += __shfl_xor(sq, 2);
        sq += __shfl_xor(sq, 4);
        sq += __shfl_xor(sq, 8);
        float w = lorentz_w(sq);   // issued once per wave for 4 edges
        ax = fmaf(hs.x, w, ax);
        ay = fmaf(hs.y, w, ay);
        az = fmaf(hs.z, w, az);
        aw = fmaf(hs.w, w, aw);
    }
    float inv = 1.0f / (deg > 1 ? (float)deg : 1.0f);
    float4 o;
    o.x = fmaxf(ax * inv, 0.0f);
    o.y = fmaxf(ay * inv, 0.0f);
    o.z = fmaxf(az * inv, 0.0f);
    o.w = fmaxf(aw * inv, 0.0f);
    *reinterpret_cast<float4*>(hidden + (size_t)node * 64 + gl * 4) = o;
}

// ---- layer-2 fused gather-aggregate: w from hidden (64ch), message from h2 (32ch). ----
__global__ void agg2_out(const float* __restrict__ hidden, const float* __restrict__ h2,
                         const int* __restrict__ cursor, const int* __restrict__ cnt,
                         const int* __restrict__ src_sorted,
                         float* __restrict__ out, int N)
{
    int node = (blockIdx.x * blockDim.x + threadIdx.x) >> 4;
    int gl = threadIdx.x & 15;
    if (node >= N) return;
    int deg = cnt[node];
    int end = cursor[node];
    int beg = end - deg;
    float4 hd = *reinterpret_cast<const float4*>(hidden + (size_t)node * 64 + gl * 4);
    float ax = 0.f, ay = 0.f;
    for (int p = beg; p < end; ++p) {
        int s = src_sorted[p];
        float4 hs = *reinterpret_cast<const float4*>(hidden + (size_t)s * 64 + gl * 4);
        float2 ms = *reinterpret_cast<const float2*>(h2 + (size_t)s * 32 + gl * 2);
        float dx = hs.x - hd.x, dy = hs.y - hd.y, dz = hs.z - hd.z, dw = hs.w - hd.w;
        float sq = dx * dx;
        sq = fmaf(dy, dy, sq);
        sq = fmaf(dz, dz, sq);
        sq = fmaf(dw, dw, sq);
        sq += __shfl_xor(sq, 1);
        sq += __shfl_xor(sq, 2);
        sq += __shfl_xor(sq, 4);
        sq += __shfl_xor(sq, 8);
        float w = lorentz_w(sq);
        ax = fmaf(ms.x, w, ax);
        ay = fmaf(ms.y, w, ay);
    }
    float inv = 1.0f / (deg > 1 ? (float)deg : 1.0f);
    float2 o;
    o.x = ax * inv;
    o.y = ay * inv;
    *reinterpret_cast<float2*>(out + (size_t)node * 32 + gl * 2) = o;
}

extern "C" void kernel_launch(void* const* d_in, const int* in_sizes, int n_in,
                              void* d_out, int out_size, void* d_ws, size_t ws_size,
                              hipStream_t stream)
{
    const float* x  = (const float*)d_in[0];
    const int*   ei = (const int*)d_in[1];
    const float* W1 = (const float*)d_in[2];
    const float* b1 = (const float*)d_in[3];
    const float* W2 = (const float*)d_in[4];
    const float* b2 = (const float*)d_in[5];
    float* out = (float*)d_out;

    const int N = in_sizes[0] / 64;
    const int E = in_sizes[1] / 2;
    const int* src = ei;
    const int* dst = ei + E;

    float* ws = (float*)d_ws;
    float* h1     = ws;                               // N*64 (reused as h2 = N*32 later)
    float* hidden = h1 + (size_t)N * 64;              // N*64
    int*   cnt    = (int*)(hidden + (size_t)N * 64);  // N
    int*   cursor = cnt + N;                          // N
    int*   src_sorted = cursor + N;                   // E
    float* h2     = h1;                               // alias: h1 dead after agg1_relu

    hipMemsetAsync(cnt, 0, (size_t)N * sizeof(int), stream);

    int eblk = (E + 255) / 256;
    count_dst<<<eblk, 256, 0, stream>>>(dst, cnt, E);
    scan_excl<<<1, 1024, 0, stream>>>(cnt, cursor, N);
    scatter_edges<<<eblk, 256, 0, stream>>>(src, dst, cursor, src_sorted, E);

    linear64<<<(N + 3) / 4, 256, 0, stream>>>(x, W1, b1, h1, N);

    int gblk = (int)(((size_t)N * 16 + 255) / 256);   // 16 lanes per node
    agg1_relu<<<gblk, 256, 0, stream>>>(x, h1, cursor, cnt, src_sorted, hidden, N);

    linear32<<<(N + 7) / 8, 256, 0, stream>>>(hidden, W2, b2, h2, N);

    agg2_out<<<gblk, 256, 0, stream>>>(hidden, h2, cursor, cnt, src_sorted, out, N);
}

// Round 4
// 539.041 us; speedup vs baseline: 1.8484x; 1.2657x over previous
//
#include <hip/hip_runtime.h>
#include <math.h>

#define MAX_VEL 0.9f
#define REL_EPS 1e-6f

// Lorentz time-dilation weight from squared distance.
// w = sqrt(1 - (0.9*tanh(r))^2 + eps), tanh via fast exp: th = 1 - 2/(e^{2r}+1).
__device__ __forceinline__ float lorentz_w(float sq)
{
    float r = sqrtf(sq);
    float e = __expf(2.0f * r);
    float th = 1.0f - 2.0f / (e + 1.0f);
    return sqrtf(fmaf(-(MAX_VEL * MAX_VEL), th * th, 1.0f + REL_EPS));
}

// ---------------- dense linear: Y[N,64] = X[N,64] @ W[64,64] + b ----------------
__global__ void linear64(const float* __restrict__ X, const float* __restrict__ W,
                         const float* __restrict__ b, float* __restrict__ Y, int N)
{
    __shared__ float sW[64 * 64];
    __shared__ float sB[64];
    for (int i = threadIdx.x; i < 64 * 64; i += blockDim.x) sW[i] = W[i];
    if (threadIdx.x < 64) sB[threadIdx.x] = b[threadIdx.x];
    __syncthreads();
    int node = blockIdx.x * 4 + (threadIdx.x >> 6);
    int c = threadIdx.x & 63;
    if (node >= N) return;
    const float* xr = X + (size_t)node * 64;
    float acc = sB[c];
#pragma unroll
    for (int k = 0; k < 64; k += 4) {
        float4 xv = *reinterpret_cast<const float4*>(xr + k);
        acc = fmaf(xv.x, sW[(k + 0) * 64 + c], acc);
        acc = fmaf(xv.y, sW[(k + 1) * 64 + c], acc);
        acc = fmaf(xv.z, sW[(k + 2) * 64 + c], acc);
        acc = fmaf(xv.w, sW[(k + 3) * 64 + c], acc);
    }
    Y[(size_t)node * 64 + c] = acc;
}

// ---------------- dense linear: Y[N,32] = X[N,64] @ W[64,32] + b ----------------
__global__ void linear32(const float* __restrict__ X, const float* __restrict__ W,
                         const float* __restrict__ b, float* __restrict__ Y, int N)
{
    __shared__ float sW[64 * 32];
    __shared__ float sB[32];
    for (int i = threadIdx.x; i < 64 * 32; i += blockDim.x) sW[i] = W[i];
    if (threadIdx.x < 32) sB[threadIdx.x] = b[threadIdx.x];
    __syncthreads();
    int node = blockIdx.x * 8 + (threadIdx.x >> 5);
    int c = threadIdx.x & 31;
    if (node >= N) return;
    const float* xr = X + (size_t)node * 64;
    float acc = sB[c];
#pragma unroll
    for (int k = 0; k < 64; k += 4) {
        float4 xv = *reinterpret_cast<const float4*>(xr + k);
        acc = fmaf(xv.x, sW[(k + 0) * 32 + c], acc);
        acc = fmaf(xv.y, sW[(k + 1) * 32 + c], acc);
        acc = fmaf(xv.z, sW[(k + 2) * 32 + c], acc);
        acc = fmaf(xv.w, sW[(k + 3) * 32 + c], acc);
    }
    Y[(size_t)node * 32 + c] = acc;
}

// ---------------- CSR build: histogram of dst ----------------
__global__ void count_dst(const int* __restrict__ dst, int* __restrict__ cnt, int E)
{
    int e = blockIdx.x * blockDim.x + threadIdx.x;
    if (e < E) atomicAdd(&cnt[dst[e]], 1);
}

// ---------------- device-wide exclusive scan, 3 kernels ----------------
// pass 1: per-block (1024 elements) total -> bsum[blockIdx]
__global__ void scan_part1(const int* __restrict__ cnt, int* __restrict__ bsum, int N)
{
    int base = blockIdx.x * 1024 + threadIdx.x * 4;
    int s = 0;
    if (base + 3 < N) {
        int4 v = *reinterpret_cast<const int4*>(cnt + base);
        s = v.x + v.y + v.z + v.w;
    } else {
        for (int i = 0; i < 4; ++i) if (base + i < N) s += cnt[base + i];
    }
#pragma unroll
    for (int off = 32; off; off >>= 1) s += __shfl_xor(s, off);
    __shared__ int ws[4];
    if ((threadIdx.x & 63) == 0) ws[threadIdx.x >> 6] = s;
    __syncthreads();
    if (threadIdx.x == 0) bsum[blockIdx.x] = ws[0] + ws[1] + ws[2] + ws[3];
}

// pass 2: exclusive scan of block sums (NB <= 256), one block
__global__ void scan_bsums(int* __restrict__ bsum, int NB)
{
    __shared__ int s[256];
    int t = threadIdx.x;
    int v = (t < NB) ? bsum[t] : 0;
    s[t] = v;
    __syncthreads();
    for (int off = 1; off < 256; off <<= 1) {
        int add = (t >= off) ? s[t - off] : 0;
        __syncthreads();
        s[t] += add;
        __syncthreads();
    }
    if (t < NB) bsum[t] = s[t] - v;   // exclusive
}

// pass 3: per-element exclusive scan with block offset -> cursor
__global__ void scan_part2(const int* __restrict__ cnt, const int* __restrict__ bsum,
                           int* __restrict__ cursor, int N)
{
    int t = threadIdx.x;
    int base = blockIdx.x * 1024 + t * 4;
    int4 v = make_int4(0, 0, 0, 0);
    if (base + 3 < N) {
        v = *reinterpret_cast<const int4*>(cnt + base);
    } else if (base < N) {
        int* p = (int*)&v;
        for (int i = 0; i < 4; ++i) if (base + i < N) p[i] = cnt[base + i];
    }
    int tsum = v.x + v.y + v.z + v.w;
    int inc = tsum;
    int lane = t & 63;
#pragma unroll
    for (int off = 1; off < 64; off <<= 1) {
        int u = __shfl_up(inc, off);
        if (lane >= off) inc += u;
    }
    __shared__ int wtot[4];
    if (lane == 63) wtot[t >> 6] = inc;
    __syncthreads();
    int wid = t >> 6;
    int woff = 0;
    for (int i = 0; i < wid; ++i) woff += wtot[i];
    int excl = woff + (inc - tsum) + bsum[blockIdx.x];
    if (base < N) {
        int4 o;
        o.x = excl;
        o.y = excl + v.x;
        o.z = o.y + v.y;
        o.w = o.z + v.z;
        if (base + 3 < N) {
            *reinterpret_cast<int4*>(cursor + base) = o;
        } else {
            int* p = (int*)&o;
            for (int i = 0; i < 4; ++i) if (base + i < N) cursor[base + i] = p[i];
        }
    }
}

// ---------------- CSR build: scatter src ids into dst-sorted order ----------------
// After this kernel, cursor[i] == rowptr[i+1] (inclusive prefix).
__global__ void scatter_edges(const int* __restrict__ src, const int* __restrict__ dst,
                              int* __restrict__ cursor, int* __restrict__ src_sorted, int E)
{
    int e = blockIdx.x * blockDim.x + threadIdx.x;
    if (e < E) {
        int p = atomicAdd(&cursor[dst[e]], 1);
        src_sorted[p] = src[e];
    }
}

// ---- layer-1 fused gather-aggregate: 16-lane group per node, float4 per lane. ----
__global__ void agg1_relu(const float* __restrict__ x, const float* __restrict__ h1,
                          const int* __restrict__ cursor, const int* __restrict__ cnt,
                          const int* __restrict__ src_sorted,
                          float* __restrict__ hidden, int N)
{
    int node = (blockIdx.x * blockDim.x + threadIdx.x) >> 4;
    int gl = threadIdx.x & 15;
    if (node >= N) return;
    int deg = cnt[node];
    int end = cursor[node];     // inclusive prefix after scatter
    int beg = end - deg;
    float4 xd = *reinterpret_cast<const float4*>(x + (size_t)node * 64 + gl * 4);
    float ax = 0.f, ay = 0.f, az = 0.f, aw = 0.f;
    for (int p = beg; p < end; ++p) {
        int s = src_sorted[p];
        float4 xs = *reinterpret_cast<const float4*>(x + (size_t)s * 64 + gl * 4);
        float4 hs = *reinterpret_cast<const float4*>(h1 + (size_t)s * 64 + gl * 4);
        float dx = xs.x - xd.x, dy = xs.y - xd.y, dz = xs.z - xd.z, dw = xs.w - xd.w;
        float sq = dx * dx;
        sq = fmaf(dy, dy, sq);
        sq = fmaf(dz, dz, sq);
        sq = fmaf(dw, dw, sq);
        sq += __shfl_xor(sq, 1);
        sq += __shfl_xor(sq, 2);
        sq += __shfl_xor(sq, 4);
        sq += __shfl_xor(sq, 8);
        float w = lorentz_w(sq);   // one wave op covers 4 edges
        ax = fmaf(hs.x, w, ax);
        ay = fmaf(hs.y, w, ay);
        az = fmaf(hs.z, w, az);
        aw = fmaf(hs.w, w, aw);
    }
    float inv = 1.0f / (deg > 1 ? (float)deg : 1.0f);
    float4 o;
    o.x = fmaxf(ax * inv, 0.0f);
    o.y = fmaxf(ay * inv, 0.0f);
    o.z = fmaxf(az * inv, 0.0f);
    o.w = fmaxf(aw * inv, 0.0f);
    *reinterpret_cast<float4*>(hidden + (size_t)node * 64 + gl * 4) = o;
}

// ---- layer-2 fused gather-aggregate: w from hidden (64ch), message from h2 (32ch). ----
__global__ void agg2_out(const float* __restrict__ hidden, const float* __restrict__ h2,
                         const int* __restrict__ cursor, const int* __restrict__ cnt,
                         const int* __restrict__ src_sorted,
                         float* __restrict__ out, int N)
{
    int node = (blockIdx.x * blockDim.x + threadIdx.x) >> 4;
    int gl = threadIdx.x & 15;
    if (node >= N) return;
    int deg = cnt[node];
    int end = cursor[node];
    int beg = end - deg;
    float4 hd = *reinterpret_cast<const float4*>(hidden + (size_t)node * 64 + gl * 4);
    float ax = 0.f, ay = 0.f;
    for (int p = beg; p < end; ++p) {
        int s = src_sorted[p];
        float4 hs = *reinterpret_cast<const float4*>(hidden + (size_t)s * 64 + gl * 4);
        float2 ms = *reinterpret_cast<const float2*>(h2 + (size_t)s * 32 + gl * 2);
        float dx = hs.x - hd.x, dy = hs.y - hd.y, dz = hs.z - hd.z, dw = hs.w - hd.w;
        float sq = dx * dx;
        sq = fmaf(dy, dy, sq);
        sq = fmaf(dz, dz, sq);
        sq = fmaf(dw, dw, sq);
        sq += __shfl_xor(sq, 1);
        sq += __shfl_xor(sq, 2);
        sq += __shfl_xor(sq, 4);
        sq += __shfl_xor(sq, 8);
        float w = lorentz_w(sq);
        ax = fmaf(ms.x, w, ax);
        ay = fmaf(ms.y, w, ay);
    }
    float inv = 1.0f / (deg > 1 ? (float)deg : 1.0f);
    float2 o;
    o.x = ax * inv;
    o.y = ay * inv;
    *reinterpret_cast<float2*>(out + (size_t)node * 32 + gl * 2) = o;
}

extern "C" void kernel_launch(void* const* d_in, const int* in_sizes, int n_in,
                              void* d_out, int out_size, void* d_ws, size_t ws_size,
                              hipStream_t stream)
{
    const float* x  = (const float*)d_in[0];
    const int*   ei = (const int*)d_in[1];
    const float* W1 = (const float*)d_in[2];
    const float* b1 = (const float*)d_in[3];
    const float* W2 = (const float*)d_in[4];
    const float* b2 = (const float*)d_in[5];
    float* out = (float*)d_out;

    const int N = in_sizes[0] / 64;
    const int E = in_sizes[1] / 2;
    const int* src = ei;
    const int* dst = ei + E;

    float* ws = (float*)d_ws;
    float* h1     = ws;                               // N*64 (reused as h2 = N*32 later)
    float* hidden = h1 + (size_t)N * 64;              // N*64
    int*   cnt    = (int*)(hidden + (size_t)N * 64);  // N
    int*   cursor = cnt + N;                          // N
    int*   bsum   = cursor + N;                       // <=256
    int*   src_sorted = bsum + 256;                   // E
    float* h2     = h1;                               // alias: h1 dead after agg1_relu

    hipMemsetAsync(cnt, 0, (size_t)N * sizeof(int), stream);

    int eblk = (E + 255) / 256;
    count_dst<<<eblk, 256, 0, stream>>>(dst, cnt, E);

    int NB = (N + 1023) / 1024;                       // 98 for N=100k (<=256)
    scan_part1<<<NB, 256, 0, stream>>>(cnt, bsum, N);
    scan_bsums<<<1, 256, 0, stream>>>(bsum, NB);
    scan_part2<<<NB, 256, 0, stream>>>(cnt, bsum, cursor, N);

    scatter_edges<<<eblk, 256, 0, stream>>>(src, dst, cursor, src_sorted, E);

    linear64<<<(N + 3) / 4, 256, 0, stream>>>(x, W1, b1, h1, N);

    int gblk = (int)(((size_t)N * 16 + 255) / 256);   // 16 lanes per node
    agg1_relu<<<gblk, 256, 0, stream>>>(x, h1, cursor, cnt, src_sorted, hidden, N);

    linear32<<<(N + 7) / 8, 256, 0, stream>>>(hidden, W2, b2, h2, N);

    agg2_out<<<gblk, 256, 0, stream>>>(hidden, h2, cursor, cnt, src_sorted, out, N);
}

// Round 5
// 435.821 us; speedup vs baseline: 2.2861x; 1.2368x over previous
//
#include <hip/hip_runtime.h>
#include <math.h>

#define MAX_VEL 0.9f
#define REL_EPS 1e-6f

// Lorentz time-dilation weight from squared distance.
// w = sqrt(1 - (0.9*tanh(r))^2 + eps), tanh via fast exp: th = 1 - 2/(e^{2r}+1).
__device__ __forceinline__ float lorentz_w(float sq)
{
    float r = sqrtf(sq);
    float e = __expf(2.0f * r);
    float th = 1.0f - 2.0f / (e + 1.0f);
    return sqrtf(fmaf(-(MAX_VEL * MAX_VEL), th * th, 1.0f + REL_EPS));
}

// ---------------- CSR build: histogram of dst ----------------
__global__ void count_dst(const int* __restrict__ dst, int* __restrict__ cnt, int E)
{
    int e = blockIdx.x * blockDim.x + threadIdx.x;
    if (e < E) atomicAdd(&cnt[dst[e]], 1);
}

// ---------------- device-wide exclusive scan, 3 kernels ----------------
__global__ void scan_part1(const int* __restrict__ cnt, int* __restrict__ bsum, int N)
{
    int base = blockIdx.x * 1024 + threadIdx.x * 4;
    int s = 0;
    if (base + 3 < N) {
        int4 v = *reinterpret_cast<const int4*>(cnt + base);
        s = v.x + v.y + v.z + v.w;
    } else {
        for (int i = 0; i < 4; ++i) if (base + i < N) s += cnt[base + i];
    }
#pragma unroll
    for (int off = 32; off; off >>= 1) s += __shfl_xor(s, off);
    __shared__ int ws[4];
    if ((threadIdx.x & 63) == 0) ws[threadIdx.x >> 6] = s;
    __syncthreads();
    if (threadIdx.x == 0) bsum[blockIdx.x] = ws[0] + ws[1] + ws[2] + ws[3];
}

__global__ void scan_bsums(int* __restrict__ bsum, int NB)
{
    __shared__ int s[256];
    int t = threadIdx.x;
    int v = (t < NB) ? bsum[t] : 0;
    s[t] = v;
    __syncthreads();
    for (int off = 1; off < 256; off <<= 1) {
        int add = (t >= off) ? s[t - off] : 0;
        __syncthreads();
        s[t] += add;
        __syncthreads();
    }
    if (t < NB) bsum[t] = s[t] - v;   // exclusive
}

__global__ void scan_part2(const int* __restrict__ cnt, const int* __restrict__ bsum,
                           int* __restrict__ cursor, int N)
{
    int t = threadIdx.x;
    int base = blockIdx.x * 1024 + t * 4;
    int4 v = make_int4(0, 0, 0, 0);
    if (base + 3 < N) {
        v = *reinterpret_cast<const int4*>(cnt + base);
    } else if (base < N) {
        int* p = (int*)&v;
        for (int i = 0; i < 4; ++i) if (base + i < N) p[i] = cnt[base + i];
    }
    int tsum = v.x + v.y + v.z + v.w;
    int inc = tsum;
    int lane = t & 63;
#pragma unroll
    for (int off = 1; off < 64; off <<= 1) {
        int u = __shfl_up(inc, off);
        if (lane >= off) inc += u;
    }
    __shared__ int wtot[4];
    if (lane == 63) wtot[t >> 6] = inc;
    __syncthreads();
    int wid = t >> 6;
    int woff = 0;
    for (int i = 0; i < wid; ++i) woff += wtot[i];
    int excl = woff + (inc - tsum) + bsum[blockIdx.x];
    if (base < N) {
        int4 o;
        o.x = excl;
        o.y = excl + v.x;
        o.z = o.y + v.y;
        o.w = o.z + v.z;
        if (base + 3 < N) {
            *reinterpret_cast<int4*>(cursor + base) = o;
        } else {
            int* p = (int*)&o;
            for (int i = 0; i < 4; ++i) if (base + i < N) cursor[base + i] = p[i];
        }
    }
}

// ---------------- CSR scatter, XCD-partitioned by dst range ----------------
// blockIdx&7 selects an XCD-class (round-robin dispatch heuristic); each class
// scans all edges but commits only dsts in its 1/8 range -> src_sorted lines are
// written from one XCD's L2 only (no cross-XCD line ping-pong).
// After this kernel, cursor[i] == rowptr[i+1] (inclusive prefix).
#define SC_EPB 1024
__global__ void scatter_edges_xcd(const int* __restrict__ src, const int* __restrict__ dst,
                                  int* __restrict__ cursor, int* __restrict__ src_sorted,
                                  int E, int N)
{
    int xcd = blockIdx.x & 7;
    int seg = blockIdx.x >> 3;
    int lo = (int)(((long long)N * xcd) >> 3);
    int hi = (int)(((long long)N * (xcd + 1)) >> 3);
    int base = seg * SC_EPB + threadIdx.x * 4;
    if (base >= E) return;
    int4 d4, s4;
    if (base + 3 < E) {
        d4 = *reinterpret_cast<const int4*>(dst + base);
        s4 = *reinterpret_cast<const int4*>(src + base);
    } else {
        int* dp = (int*)&d4; int* sp = (int*)&s4;
        for (int i = 0; i < 4; ++i) {
            dp[i] = (base + i < E) ? dst[base + i] : -1;
            sp[i] = (base + i < E) ? src[base + i] : 0;
        }
    }
    const int* dp = (const int*)&d4;
    const int* sp = (const int*)&s4;
#pragma unroll
    for (int i = 0; i < 4; ++i) {
        int d = dp[i];
        if (d >= lo && d < hi) {
            int p = atomicAdd(&cursor[d], 1);
            src_sorted[p] = sp[i];
        }
    }
}

// ---- layer-1 aggregate on RAW x: aggx[n] = sum_s w*x[s], sumw[n] = sum_s w ----
// 16-lane group per node, float4 per lane; x[node] row serves the diff.
__global__ void agg1x(const float* __restrict__ x, const int* __restrict__ cursor,
                      const int* __restrict__ cnt, const int* __restrict__ src_sorted,
                      float* __restrict__ aggx, float* __restrict__ sumw, int N)
{
    int node = (blockIdx.x * blockDim.x + threadIdx.x) >> 4;
    int gl = threadIdx.x & 15;
    if (node >= N) return;
    int deg = cnt[node];
    int end = cursor[node];     // inclusive prefix after scatter
    int beg = end - deg;
    float4 xd = *reinterpret_cast<const float4*>(x + (size_t)node * 64 + gl * 4);
    float ax = 0.f, ay = 0.f, az = 0.f, aw = 0.f, sw = 0.f;
    for (int p = beg; p < end; ++p) {
        int s = src_sorted[p];
        float4 xs = *reinterpret_cast<const float4*>(x + (size_t)s * 64 + gl * 4);
        float dx = xs.x - xd.x, dy = xs.y - xd.y, dz = xs.z - xd.z, dw = xs.w - xd.w;
        float sq = dx * dx;
        sq = fmaf(dy, dy, sq);
        sq = fmaf(dz, dz, sq);
        sq = fmaf(dw, dw, sq);
        sq += __shfl_xor(sq, 1);
        sq += __shfl_xor(sq, 2);
        sq += __shfl_xor(sq, 4);
        sq += __shfl_xor(sq, 8);
        float w = lorentz_w(sq);   // one wave op covers 4 edges
        sw += w;
        ax = fmaf(xs.x, w, ax);
        ay = fmaf(xs.y, w, ay);
        az = fmaf(xs.z, w, az);
        aw = fmaf(xs.w, w, aw);
    }
    float4 o; o.x = ax; o.y = ay; o.z = az; o.w = aw;
    *reinterpret_cast<float4*>(aggx + (size_t)node * 64 + gl * 4) = o;
    if (gl == 0) sumw[node] = sw;
}

// ---- post-linear 1: hidden = relu( (aggx@W1 + b1*sumw) / max(deg,1) ) ----
__global__ void lin1_post(const float* __restrict__ aggx, const float* __restrict__ W1,
                          const float* __restrict__ b1, const float* __restrict__ sumw,
                          const int* __restrict__ cnt, float* __restrict__ hidden, int N)
{
    __shared__ float sW[64 * 64];
    __shared__ float sB[64];
    for (int i = threadIdx.x; i < 64 * 64; i += blockDim.x) sW[i] = W1[i];
    if (threadIdx.x < 64) sB[threadIdx.x] = b1[threadIdx.x];
    __syncthreads();
    int node = blockIdx.x * 4 + (threadIdx.x >> 6);
    int c = threadIdx.x & 63;
    if (node >= N) return;
    const float* ar = aggx + (size_t)node * 64;
    float acc = 0.0f;
#pragma unroll
    for (int k = 0; k < 64; k += 4) {
        float4 av = *reinterpret_cast<const float4*>(ar + k);
        acc = fmaf(av.x, sW[(k + 0) * 64 + c], acc);
        acc = fmaf(av.y, sW[(k + 1) * 64 + c], acc);
        acc = fmaf(av.z, sW[(k + 2) * 64 + c], acc);
        acc = fmaf(av.w, sW[(k + 3) * 64 + c], acc);
    }
    int dg = cnt[node];
    float inv = 1.0f / (dg > 1 ? (float)dg : 1.0f);
    float val = (acc + sB[c] * sumw[node]) * inv;
    hidden[(size_t)node * 64 + c] = fmaxf(val, 0.0f);
}

// ---- layer-2 aggregate on hidden: aggh[n] = sum_s w*hidden[s], sumw[n] = sum_s w ----
__global__ void agg2h(const float* __restrict__ hidden, const int* __restrict__ cursor,
                      const int* __restrict__ cnt, const int* __restrict__ src_sorted,
                      float* __restrict__ aggh, float* __restrict__ sumw, int N)
{
    int node = (blockIdx.x * blockDim.x + threadIdx.x) >> 4;
    int gl = threadIdx.x & 15;
    if (node >= N) return;
    int deg = cnt[node];
    int end = cursor[node];
    int beg = end - deg;
    float4 hd = *reinterpret_cast<const float4*>(hidden + (size_t)node * 64 + gl * 4);
    float ax = 0.f, ay = 0.f, az = 0.f, aw = 0.f, sw = 0.f;
    for (int p = beg; p < end; ++p) {
        int s = src_sorted[p];
        float4 hs = *reinterpret_cast<const float4*>(hidden + (size_t)s * 64 + gl * 4);
        float dx = hs.x - hd.x, dy = hs.y - hd.y, dz = hs.z - hd.z, dw = hs.w - hd.w;
        float sq = dx * dx;
        sq = fmaf(dy, dy, sq);
        sq = fmaf(dz, dz, sq);
        sq = fmaf(dw, dw, sq);
        sq += __shfl_xor(sq, 1);
        sq += __shfl_xor(sq, 2);
        sq += __shfl_xor(sq, 4);
        sq += __shfl_xor(sq, 8);
        float w = lorentz_w(sq);
        sw += w;
        ax = fmaf(hs.x, w, ax);
        ay = fmaf(hs.y, w, ay);
        az = fmaf(hs.z, w, az);
        aw = fmaf(hs.w, w, aw);
    }
    float4 o; o.x = ax; o.y = ay; o.z = az; o.w = aw;
    *reinterpret_cast<float4*>(aggh + (size_t)node * 64 + gl * 4) = o;
    if (gl == 0) sumw[node] = sw;
}

// ---- post-linear 2: out = (aggh@W2 + b2*sumw) / max(deg,1) ----
__global__ void lin2_post(const float* __restrict__ aggh, const float* __restrict__ W2,
                          const float* __restrict__ b2, const float* __restrict__ sumw,
                          const int* __restrict__ cnt, float* __restrict__ out, int N)
{
    __shared__ float sW[64 * 32];
    __shared__ float sB[32];
    for (int i = threadIdx.x; i < 64 * 32; i += blockDim.x) sW[i] = W2[i];
    if (threadIdx.x < 32) sB[threadIdx.x] = b2[threadIdx.x];
    __syncthreads();
    int node = blockIdx.x * 8 + (threadIdx.x >> 5);
    int c = threadIdx.x & 31;
    if (node >= N) return;
    const float* ar = aggh + (size_t)node * 64;
    float acc = 0.0f;
#pragma unroll
    for (int k = 0; k < 64; k += 4) {
        float4 av = *reinterpret_cast<const float4*>(ar + k);
        acc = fmaf(av.x, sW[(k + 0) * 32 + c], acc);
        acc = fmaf(av.y, sW[(k + 1) * 32 + c], acc);
        acc = fmaf(av.z, sW[(k + 2) * 32 + c], acc);
        acc = fmaf(av.w, sW[(k + 3) * 32 + c], acc);
    }
    int dg = cnt[node];
    float inv = 1.0f / (dg > 1 ? (float)dg : 1.0f);
    out[(size_t)node * 32 + c] = (acc + sB[c] * sumw[node]) * inv;
}

extern "C" void kernel_launch(void* const* d_in, const int* in_sizes, int n_in,
                              void* d_out, int out_size, void* d_ws, size_t ws_size,
                              hipStream_t stream)
{
    const float* x  = (const float*)d_in[0];
    const int*   ei = (const int*)d_in[1];
    const float* W1 = (const float*)d_in[2];
    const float* b1 = (const float*)d_in[3];
    const float* W2 = (const float*)d_in[4];
    const float* b2 = (const float*)d_in[5];
    float* out = (float*)d_out;

    const int N = in_sizes[0] / 64;
    const int E = in_sizes[1] / 2;
    const int* src = ei;
    const int* dst = ei + E;

    float* ws = (float*)d_ws;
    float* agg    = ws;                               // N*64 (aggx, then aggh)
    float* hidden = agg + (size_t)N * 64;             // N*64
    float* sumw   = hidden + (size_t)N * 64;          // N (layer1, then layer2)
    int*   cnt    = (int*)(sumw + N);                 // N
    int*   cursor = cnt + N;                          // N
    int*   bsum   = cursor + N;                       // <=256
    int*   src_sorted = bsum + 256;                   // E

    hipMemsetAsync(cnt, 0, (size_t)N * sizeof(int), stream);

    int eblk = (E + 255) / 256;
    count_dst<<<eblk, 256, 0, stream>>>(dst, cnt, E);

    int NB = (N + 1023) / 1024;                       // 98 for N=100k (<=256)
    scan_part1<<<NB, 256, 0, stream>>>(cnt, bsum, N);
    scan_bsums<<<1, 256, 0, stream>>>(bsum, NB);
    scan_part2<<<NB, 256, 0, stream>>>(cnt, bsum, cursor, N);

    int nseg = (E + SC_EPB - 1) / SC_EPB;
    scatter_edges_xcd<<<nseg * 8, 256, 0, stream>>>(src, dst, cursor, src_sorted, E, N);

    int gblk = (int)(((size_t)N * 16 + 255) / 256);   // 16 lanes per node
    agg1x<<<gblk, 256, 0, stream>>>(x, cursor, cnt, src_sorted, agg, sumw, N);
    lin1_post<<<(N + 3) / 4, 256, 0, stream>>>(agg, W1, b1, sumw, cnt, hidden, N);

    agg2h<<<gblk, 256, 0, stream>>>(hidden, cursor, cnt, src_sorted, agg, sumw, N);
    lin2_post<<<(N + 7) / 8, 256, 0, stream>>>(agg, W2, b2, sumw, cnt, out, N);
}